// Round 6
// baseline (310.515 us; speedup 1.0000x reference)
//
#include <hip/hip_runtime.h>
#include <math.h>

#define B_  4
#define T_  2048
#define D_  1024
#define H_  16
#define HD_ 64
#define CST2 0.1803368801111244f   // HD^-0.5 * log2(e): folded into Wq/bq at prep
#define LSTR 72                    // attn LDS stride (conflict-free, measured 0 conflicts)
#define DEFER_THR 8.0f
#define PL_ ((size_t)B_ * H_ * T_ * HD_)

typedef __attribute__((ext_vector_type(8)))  short s8v;
typedef __attribute__((ext_vector_type(4)))  float f4v;
typedef __attribute__((ext_vector_type(16))) float f16v;
typedef __attribute__((ext_vector_type(8)))  unsigned short u8v;
typedef __attribute__((ext_vector_type(4)))  unsigned short u4v;
typedef __attribute__((ext_vector_type(4)))  unsigned int  u32x4;

static __device__ __forceinline__ unsigned short f2b(float f) {
    unsigned u = __builtin_bit_cast(unsigned, f);
    u = (u + 0x7fffu + ((u >> 16) & 1u)) >> 16;   // RNE
    return (unsigned short)u;
}
static __device__ __forceinline__ f4v mfma16(s8v a, s8v b, f4v c) {
    return __builtin_amdgcn_mfma_f32_16x16x32_bf16(a, b, c, 0, 0, 0);
}
static __device__ __forceinline__ f16v mfma32(s8v a, s8v b, f16v c) {
    return __builtin_amdgcn_mfma_f32_32x32x16_bf16(a, b, c, 0, 0, 0);
}
// async global->LDS, 16B per lane; LDS dest = wave-uniform base + lane*16
static __device__ __forceinline__ void gl_lds16(const void* gsrc, void* lds) {
    __builtin_amdgcn_global_load_lds(
        (const __attribute__((address_space(1))) void*)gsrc,
        (__attribute__((address_space(3))) void*)lds,
        16, 0, 0);
}

// ---------------------------------------------------------------------------
// Prep 1: fp32 -> bf16 convert (x, Wp)
// ---------------------------------------------------------------------------
__global__ void cvt_f2b_kernel(const float* __restrict__ src,
                               unsigned short* __restrict__ dst, int n4) {
    int i = blockIdx.x * blockDim.x + threadIdx.x;
    int stride = gridDim.x * blockDim.x;
    for (; i < n4; i += stride) {
        float4 v = reinterpret_cast<const float4*>(src)[i];
        u4v o;
        o[0] = f2b(v.x); o[1] = f2b(v.y); o[2] = f2b(v.z); o[3] = f2b(v.w);
        reinterpret_cast<u4v*>(dst)[i] = o;
    }
}

// ---------------------------------------------------------------------------
// Prep 2: Wq/Wk/Wv [sel][h][k][e] fp32 -> Wb [sel*16+h][e][k] bf16 (transposed)
// Wq pre-scaled by CST2 (softmax scale folded into Q).
// ---------------------------------------------------------------------------
__global__ __launch_bounds__(256) void cvt_wqkv(
    const float* __restrict__ Wq, const float* __restrict__ Wk,
    const float* __restrict__ Wv, unsigned short* __restrict__ Wb) {
    const int tid = threadIdx.x;
    const int kblk = blockIdx.x;          // 0..7
    const int by = blockIdx.y;            // sel*16+h
    const int sel = by >> 4, h = by & 15;
    const float* W = (sel == 0 ? Wq : sel == 1 ? Wk : Wv) + (size_t)h * D_ * HD_ + (size_t)kblk * 128 * HD_;
    const float scl = (sel == 0) ? CST2 : 1.0f;

    __shared__ unsigned short L[128 * 68];

    #pragma unroll
    for (int p = 0; p < 8; ++p) {
        int flat = p * 256 + tid;
        int r = flat >> 4, e4 = (flat & 15) * 4;
        float4 v = *(const float4*)&W[(size_t)r * HD_ + e4];
        L[r * 68 + e4 + 0] = f2b(v.x * scl);
        L[r * 68 + e4 + 1] = f2b(v.y * scl);
        L[r * 68 + e4 + 2] = f2b(v.z * scl);
        L[r * 68 + e4 + 3] = f2b(v.w * scl);
    }
    __syncthreads();
    #pragma unroll
    for (int p = 0; p < 8; ++p) {
        int flat = p * 256 + tid;
        int e = flat >> 5, rc = (flat & 31) * 4;
        u4v o;
        o[0] = L[(rc + 0) * 68 + e];
        o[1] = L[(rc + 1) * 68 + e];
        o[2] = L[(rc + 2) * 68 + e];
        o[3] = L[(rc + 3) * 68 + e];
        *(u4v*)&Wb[((size_t)by * HD_ + e) * D_ + kblk * 128 + rc] = o;
    }
}

// ---------------------------------------------------------------------------
// Kernel 1: fused QKV projection. BM=128, BN=128 (two heads), BK=64.
// m97 structure: global_load_lds(16B) staging into LINEAR LDS, 2 barriers/K-step.
// Q/K written [b,h,t,e]; V written TRANSPOSED [b,h,e,t].
// ---------------------------------------------------------------------------
__global__ __launch_bounds__(256) void qkv_mm(
    const unsigned short* __restrict__ xb, const unsigned short* __restrict__ Wb,
    const float* __restrict__ bq, const float* __restrict__ bk_,
    const float* __restrict__ bv, unsigned short* __restrict__ qkvb) {
    const int tid = threadIdx.x;
    const int m0 = blockIdx.x * 128;
    const int by = blockIdx.y;            // sel*8 + hp
    const int sel = by >> 3, hp = by & 7;
    const float* bias = (sel == 0 ? bq : sel == 1 ? bk_ : bv);
    const float bscale = (sel == 0) ? CST2 : 1.0f;
    const unsigned short* Wt = Wb + (size_t)(sel * 16 + 2 * hp) * HD_ * D_;

    __shared__ __align__(16) unsigned short As[128 * 64];   // linear [row][64]
    __shared__ __align__(16) unsigned short Bs[128 * 64];

    const int w = tid >> 6, lane = tid & 63;
    const int el = lane & 15, eh = lane >> 4;
    const int wm = w >> 1, wn = w & 1;
    const int r8 = lane >> 3;             // 0..7 (row within 8-row chunk)
    const int c8 = (lane & 7) * 8;        // bf16 col within row

    f4v acc[4][4];
    #pragma unroll
    for (int i = 0; i < 4; ++i)
        #pragma unroll
        for (int j = 0; j < 4; ++j) acc[i][j] = 0.f;

    for (int k0 = 0; k0 < D_; k0 += 64) {
        // stage A,B: 4 chunks each per wave; chunk c = 8 rows (1KB)
        #pragma unroll
        for (int p = 0; p < 4; ++p) {
            int c = p * 4 + w;            // 0..15
            int row = 8 * c + r8;
            gl_lds16(&xb[(size_t)(m0 + row) * D_ + k0 + c8], &As[c * 512]);
            gl_lds16(&Wt[(size_t)row * D_ + k0 + c8], &Bs[c * 512]);
        }
        __syncthreads();                  // drains vmcnt -> tiles ready
        s8v a[4][2], b[4][2];
        #pragma unroll
        for (int i = 0; i < 4; ++i)
            #pragma unroll
            for (int ks = 0; ks < 2; ++ks)
                a[i][ks] = *(const s8v*)&As[(64 * wm + 16 * i + el) * 64 + ks * 32 + eh * 8];
        #pragma unroll
        for (int j = 0; j < 4; ++j)
            #pragma unroll
            for (int ks = 0; ks < 2; ++ks)
                b[j][ks] = *(const s8v*)&Bs[(64 * wn + 16 * j + el) * 64 + ks * 32 + eh * 8];
        __builtin_amdgcn_s_setprio(1);
        #pragma unroll
        for (int i = 0; i < 4; ++i)
            #pragma unroll
            for (int j = 0; j < 4; ++j)
                #pragma unroll
                for (int ks = 0; ks < 2; ++ks)
                    acc[i][j] = mfma16(a[i][ks], b[j][ks], acc[i][j]);
        __builtin_amdgcn_s_setprio(0);
        __syncthreads();                  // reads done before next stage
    }

    if (sel == 2) {
        // V: transposed store [b][h][e][t]
        #pragma unroll
        for (int j = 0; j < 4; ++j) {
            int n = 64 * wn + 16 * j + el;
            int h2 = 2 * hp + (n >> 6);
            int e = n & 63;
            float bb = bias[h2 * HD_ + e];
            #pragma unroll
            for (int i = 0; i < 4; ++i) {
                int m = m0 + 64 * wm + 16 * i + 4 * eh;
                int bidx = m >> 11, t = m & (T_ - 1);
                u4v pk4;
                #pragma unroll
                for (int r = 0; r < 4; ++r) pk4[r] = f2b(acc[i][j][r] + bb);
                *(u4v*)&qkvb[2 * PL_ + ((size_t)(bidx * H_ + h2) * HD_ + e) * T_ + t] = pk4;
            }
        }
    } else {
        #pragma unroll
        for (int j = 0; j < 4; ++j) {
            int n = 64 * wn + 16 * j + el;
            int h2 = 2 * hp + (n >> 6);
            int e = n & 63;
            float bb = bias[h2 * HD_ + e] * bscale;
            #pragma unroll
            for (int i = 0; i < 4; ++i)
                #pragma unroll
                for (int r = 0; r < 4; ++r) {
                    int m = m0 + 64 * wm + 16 * i + 4 * eh + r;
                    int bidx = m >> 11, t = m & (T_ - 1);
                    size_t o = (((size_t)sel * B_ + bidx) * H_ + h2) * (size_t)T_ * HD_ + (size_t)t * HD_ + e;
                    qkvb[o] = f2b(acc[i][j][r] + bb);
                }
        }
    }
}

// ---------------------------------------------------------------------------
// Kernel 2: causal flash attention, swapped-QK^T in-register softmax.
// (unchanged from R5: 118 us, 0 bank conflicts, MfmaUtil 11.5%)
// ---------------------------------------------------------------------------
__global__ __launch_bounds__(512, 4) void attn_mfma(
    const unsigned short* __restrict__ qkvb, unsigned short* __restrict__ attb) {
    const int tid = threadIdx.x;
    const int by = blockIdx.y;                  // b*H+h
    const int h = by & 15, b = by >> 4;
    const int qt = gridDim.x - 1 - blockIdx.x;  // heavy tiles first
    const int q0 = qt * 256;

    const unsigned short* Qp  = qkvb + (size_t)by * T_ * HD_;
    const unsigned short* Kp  = Qp + PL_;
    const unsigned short* Vtp = qkvb + 2 * PL_ + (size_t)by * HD_ * T_;  // [e][t]

    const int w = tid >> 6, lane = tid & 63;
    const int el = lane & 31, hi = lane >> 5;
    const int qr = q0 + 32 * w;                 // wave's first q-row

    __shared__ __align__(16) unsigned short Ks[2][64 * LSTR];   // [kv][e]
    __shared__ __align__(16) unsigned short Vt[2][64 * LSTR];   // [e][kv]

    s8v aq[4];
    #pragma unroll
    for (int st = 0; st < 4; ++st)
        aq[st] = *(const s8v*)&Qp[(size_t)(qr + el) * HD_ + 16 * st + 8 * hi];

    f16v o0 = 0.f, o1 = 0.f;
    float mrow = -INFINITY, lrow = 0.f;

    const int krow = tid >> 3, kcol8 = (tid & 7) * 8;
    u8v kreg, vreg;
    kreg = *(const u8v*)&Kp[(size_t)krow * HD_ + kcol8];
    vreg = *(const u8v*)&Vtp[(size_t)krow * T_ + kcol8];
    *(u8v*)&Ks[0][krow * LSTR + kcol8] = kreg;
    *(u8v*)&Vt[0][krow * LSTR + kcol8] = vreg;

    const int ntiles = 4 * (qt + 1);
    int cur = 0;
    for (int jt = 0; jt < ntiles; ++jt) {
        const int j0 = jt * 64;
        __syncthreads();
        const bool more = (jt + 1 < ntiles);
        if (more) {
            const int jn = j0 + 64;
            kreg = *(const u8v*)&Kp[(size_t)(jn + krow) * HD_ + kcol8];
            vreg = *(const u8v*)&Vtp[(size_t)krow * T_ + jn + kcol8];
        }

        if (j0 <= qr + 31) {   // wave-uniform
            f16v s0 = 0.f, s1 = 0.f;
            __builtin_amdgcn_s_setprio(1);
            #pragma unroll
            for (int st = 0; st < 4; ++st) {
                s8v ka = *(const s8v*)&Ks[cur][(el) * LSTR + 16 * st + 8 * hi];
                s0 = mfma32(ka, aq[st], s0);
            }
            #pragma unroll
            for (int st = 0; st < 4; ++st) {
                s8v ka = *(const s8v*)&Ks[cur][(32 + el) * LSTR + 16 * st + 8 * hi];
                s1 = mfma32(ka, aq[st], s1);
            }
            __builtin_amdgcn_s_setprio(0);

            if (j0 + 63 > qr) {
                const int q = qr + el;
                #pragma unroll
                for (int r = 0; r < 16; ++r) {
                    int kv0 = j0 + (r & 3) + 8 * (r >> 2) + 4 * hi;
                    if (kv0 > q)      s0[r] = -INFINITY;
                    if (kv0 + 32 > q) s1[r] = -INFINITY;
                }
            }

            float pm = s0[0];
            #pragma unroll
            for (int r = 1; r < 16; ++r) pm = fmaxf(pm, s0[r]);
            #pragma unroll
            for (int r = 0; r < 16; ++r) pm = fmaxf(pm, s1[r]);
            pm = fmaxf(pm, __shfl_xor(pm, 32));

            if (__any(pm > mrow + DEFER_THR)) {
                float mnew = fmaxf(mrow, pm);
                float fac  = __builtin_exp2f(mrow - mnew);
                mrow = mnew;
                lrow *= fac;
                #pragma unroll
                for (int r = 0; r < 16; ++r) {
                    int qidx = (r & 3) + 8 * (r >> 2) + 4 * hi;
                    float f = __shfl(fac, qidx);
                    o0[r] *= f; o1[r] *= f;
                }
            }

            float rsum = 0.f;
            #define PV_STEP(SREG, BASE, ST)                                              \
            {                                                                            \
                float p0 = __builtin_exp2f(SREG[BASE + 0] - mrow);                       \
                float p1 = __builtin_exp2f(SREG[BASE + 1] - mrow);                       \
                float p2 = __builtin_exp2f(SREG[BASE + 2] - mrow);                       \
                float p3 = __builtin_exp2f(SREG[BASE + 3] - mrow);                       \
                float p4 = __builtin_exp2f(SREG[BASE + 4] - mrow);                       \
                float p5 = __builtin_exp2f(SREG[BASE + 5] - mrow);                       \
                float p6 = __builtin_exp2f(SREG[BASE + 6] - mrow);                       \
                float p7 = __builtin_exp2f(SREG[BASE + 7] - mrow);                       \
                rsum += ((p0 + p1) + (p2 + p3)) + ((p4 + p5) + (p6 + p7));               \
                unsigned a0, a1, a2, a3;                                                 \
                asm("v_cvt_pk_bf16_f32 %0, %1, %2" : "=v"(a0) : "v"(p0), "v"(p1));       \
                asm("v_cvt_pk_bf16_f32 %0, %1, %2" : "=v"(a1) : "v"(p2), "v"(p3));       \
                asm("v_cvt_pk_bf16_f32 %0, %1, %2" : "=v"(a2) : "v"(p4), "v"(p5));       \
                asm("v_cvt_pk_bf16_f32 %0, %1, %2" : "=v"(a3) : "v"(p6), "v"(p7));       \
                asm("v_permlane32_swap_b32 %0, %1" : "+v"(a0), "+v"(a2));                \
                asm("v_permlane32_swap_b32 %0, %1" : "+v"(a1), "+v"(a3));                \
                s8v pa = __builtin_bit_cast(s8v, (u32x4){a0, a1, a2, a3});               \
                s8v vb0 = *(const s8v*)&Vt[cur][(el) * LSTR + 16 * ST + 8 * hi];         \
                s8v vb1 = *(const s8v*)&Vt[cur][(32 + el) * LSTR + 16 * ST + 8 * hi];    \
                o0 = mfma32(pa, vb0, o0);                                                \
                o1 = mfma32(pa, vb1, o1);                                                \
            }
            PV_STEP(s0, 0, 0)
            PV_STEP(s0, 8, 1)
            PV_STEP(s1, 0, 2)
            PV_STEP(s1, 8, 3)
            #undef PV_STEP

            rsum += __shfl_xor(rsum, 32);
            lrow += rsum;
        }

        if (more) {
            *(u8v*)&Ks[cur ^ 1][krow * LSTR + kcol8] = kreg;
            *(u8v*)&Vt[cur ^ 1][krow * LSTR + kcol8] = vreg;
        }
        cur ^= 1;
    }

    float linv = 1.0f / lrow;
    #pragma unroll
    for (int r = 0; r < 16; ++r) {
        int qidx = (r & 3) + 8 * (r >> 2) + 4 * hi;
        float lv = __shfl(linv, qidx);
        size_t row = (size_t)(b * T_ + qr + qidx) * D_ + h * HD_;
        attb[row + el]      = f2b(o0[r] * lv);
        attb[row + 32 + el] = f2b(o1[r] * lv);
    }
}

// ---------------------------------------------------------------------------
// Kernel 3: output projection. BM=128, BN=128, m97-style gload_lds staging.
// ---------------------------------------------------------------------------
__global__ __launch_bounds__(256) void proj_mm(
    const unsigned short* __restrict__ ab, const unsigned short* __restrict__ Wpb,
    const float* __restrict__ bp, float* __restrict__ out) {
    const int tid = threadIdx.x;
    const int m0 = blockIdx.x * 128;
    const int n0 = blockIdx.y * 128;

    __shared__ __align__(16) unsigned short As[128 * 64];
    __shared__ __align__(16) unsigned short Bs[128 * 64];

    const int w = tid >> 6, lane = tid & 63;
    const int el = lane & 15, eh = lane >> 4;
    const int wm = w >> 1, wn = w & 1;
    const int r8 = lane >> 3;
    const int c8 = (lane & 7) * 8;

    f4v acc[4][4];
    #pragma unroll
    for (int i = 0; i < 4; ++i)
        #pragma unroll
        for (int j = 0; j < 4; ++j) acc[i][j] = 0.f;

    for (int k0 = 0; k0 < D_; k0 += 64) {
        #pragma unroll
        for (int p = 0; p < 4; ++p) {
            int c = p * 4 + w;
            int row = 8 * c + r8;
            gl_lds16(&ab[(size_t)(m0 + row) * D_ + k0 + c8], &As[c * 512]);
            gl_lds16(&Wpb[(size_t)(n0 + row) * D_ + k0 + c8], &Bs[c * 512]);
        }
        __syncthreads();
        s8v a[4][2], b[4][2];
        #pragma unroll
        for (int i = 0; i < 4; ++i)
            #pragma unroll
            for (int ks = 0; ks < 2; ++ks)
                a[i][ks] = *(const s8v*)&As[(64 * wm + 16 * i + el) * 64 + ks * 32 + eh * 8];
        #pragma unroll
        for (int j = 0; j < 4; ++j)
            #pragma unroll
            for (int ks = 0; ks < 2; ++ks)
                b[j][ks] = *(const s8v*)&Bs[(64 * wn + 16 * j + el) * 64 + ks * 32 + eh * 8];
        __builtin_amdgcn_s_setprio(1);
        #pragma unroll
        for (int i = 0; i < 4; ++i)
            #pragma unroll
            for (int j = 0; j < 4; ++j)
                #pragma unroll
                for (int ks = 0; ks < 2; ++ks)
                    acc[i][j] = mfma16(a[i][ks], b[j][ks], acc[i][j]);
        __builtin_amdgcn_s_setprio(0);
        __syncthreads();
    }
    #pragma unroll
    for (int i = 0; i < 4; ++i)
        #pragma unroll
        for (int j = 0; j < 4; ++j) {
            int n = n0 + 64 * wn + 16 * j + el;
            float bb = bp[n];
            #pragma unroll
            for (int r = 0; r < 4; ++r) {
                int m = m0 + 64 * wm + 16 * i + 4 * eh + r;
                out[(size_t)m * D_ + n] = acc[i][j][r] + bb;
            }
        }
}

// ---------------------------------------------------------------------------
extern "C" void kernel_launch(void* const* d_in, const int* in_sizes, int n_in,
                              void* d_out, int out_size, void* d_ws, size_t ws_size,
                              hipStream_t stream) {
    (void)in_sizes; (void)n_in; (void)out_size; (void)ws_size;
    const float* x  = (const float*)d_in[0];
    const float* Wq = (const float*)d_in[1];
    const float* bq = (const float*)d_in[2];
    const float* Wk = (const float*)d_in[3];
    const float* bk = (const float*)d_in[4];
    const float* Wv = (const float*)d_in[5];
    const float* bv = (const float*)d_in[6];
    const float* Wp = (const float*)d_in[7];
    const float* bp = (const float*)d_in[8];
    float* out = (float*)d_out;
    char* ws = (char*)d_ws;

    unsigned short* xb    = (unsigned short*)(ws + 0);            // 16,777,216 B
    unsigned short* Wqkvb = (unsigned short*)(ws + 16777216);     //  6,291,456 B
    unsigned short* Wpb   = (unsigned short*)(ws + 23068672);     //  2,097,152 B
    unsigned short* qkvb  = (unsigned short*)(ws + 25165824);     // 50,331,648 B
    unsigned short* attb  = (unsigned short*)(ws + 75497472);     // 16,777,216 B

    cvt_f2b_kernel<<<2048, 256, 0, stream>>>(x, xb, (B_ * T_ * D_) / 4);
    cvt_f2b_kernel<<<1024, 256, 0, stream>>>(Wp, Wpb, (D_ * D_) / 4);
    cvt_wqkv<<<dim3(8, 48), 256, 0, stream>>>(Wq, Wk, Wv, Wqkvb);
    qkv_mm<<<dim3(64, 24), 256, 0, stream>>>(xb, Wqkvb, bq, bk, bv, qkvb);
    attn_mfma<<<dim3(T_ / 256, B_ * H_), 512, 0, stream>>>(qkvb, attb);
    proj_mm<<<dim3(64, 8), 256, 0, stream>>>(attb, Wpb, bp, out);
}